// Round 9
// baseline (872.360 us; speedup 1.0000x reference)
//
#include <hip/hip_runtime.h>
#include <hip/hip_bf16.h>

typedef unsigned short u16;
typedef unsigned int u32;
typedef __attribute__((ext_vector_type(8))) short s16x8;
typedef __attribute__((ext_vector_type(4))) float f32x4;

#define MFMA_BF16(a, b, c) __builtin_amdgcn_mfma_f32_16x16x32_bf16(a, b, c, 0, 0, 0)

__device__ __forceinline__ u16 f2bf(float f) {
  union { float f; u32 u; } c; c.f = f;
  return (u16)((c.u + 0x7FFFu + ((c.u >> 16) & 1u)) >> 16);
}

__device__ __forceinline__ u32 pkbf(float a, float b) {
  float2 t; t.x = a; t.y = b;
  __hip_bfloat162 h = __float22bfloat162_rn(t);
  union { __hip_bfloat162 h; u32 u; } c; c.h = h; return c.u;
}

__device__ __forceinline__ void gll16(const void* g, void* l) {
  __builtin_amdgcn_global_load_lds((const __attribute__((address_space(1))) void*)g,
                                   (__attribute__((address_space(3))) void*)l, 16, 0, 0);
}

__device__ __forceinline__ f32x4 f4zero() { f32x4 z = {0.f, 0.f, 0.f, 0.f}; return z; }

// ---------------- prep: f32 -> bf16 convert ----------------
__global__ void cvt_bf16_kernel(const float4* __restrict__ in, u16* __restrict__ out, int n4) {
  int i = blockIdx.x * 256 + threadIdx.x;
  if (i >= n4) return;
  float4 v = in[i];
  uint2 w;
  w.x = (u32)f2bf(v.x) | ((u32)f2bf(v.y) << 16);
  w.y = (u32)f2bf(v.z) | ((u32)f2bf(v.w) << 16);
  *reinterpret_cast<uint2*>(out + (size_t)i * 4) = w;
}

// ---------------- prep: transpose + convert (R x C f32 -> C x R bf16) ----------------
__global__ void transpose_cvt_kernel(const float* __restrict__ in, u16* __restrict__ out,
                                     int R, int C) {
  __shared__ float tile[32][33];
  int tx = threadIdx.x, ty = threadIdx.y;
  int r0 = blockIdx.y * 32, c0 = blockIdx.x * 32;
#pragma unroll
  for (int i = 0; i < 32; i += 8)
    tile[ty + i][tx] = in[(size_t)(r0 + ty + i) * C + c0 + tx];
  __syncthreads();
#pragma unroll
  for (int i = 0; i < 32; i += 8)
    out[(size_t)(c0 + ty + i) * R + r0 + tx] = f2bf(tile[tx][ty + i]);
}

// =====================================================================================
// 256x256 GEMM, 2-phase ks-split K-loop with one-phase-ahead register pipelining:
//   phA: MFMA ks0 (set a) while ks1 reads (set b) drain; stage all 4 units of T+1;
//        VM0+barrier at phA-end validates the next parity.
//   phB: MFMA ks1 (set b) while next-tile ks0 reads (set a, next parity) drain.
// Counted lgkmcnt(12) (DS ops retire in order) instead of full drains; 4 barriers/tile.
// EPI 1 fuses the 256-col KV strip (cols 4096..4351), grid exactly 16x16=256 blocks:
//   KV ks0 MFMA in phA, ks1 in phB (sa = LDS A-slice row bn*16+li, bkv from wT in L2).
// WAR ledger: parity P's readers (R-ks1 at phA(t), R-ks0next at phB(t)) are drained by
// the counted lgkm waits before >=2 barriers precede P's restaging at phA(t+2).
// =====================================================================================

#define BARRIER __builtin_amdgcn_s_barrier()
#define LGKM0 asm volatile("s_waitcnt lgkmcnt(0)" ::: "memory")
#define LGKM12 asm volatile("s_waitcnt lgkmcnt(12)" ::: "memory")
#define PRIO1 __builtin_amdgcn_s_setprio(1)
#define PRIO0 __builtin_amdgcn_s_setprio(0)
#define VM0 asm volatile("s_waitcnt vmcnt(0)" ::: "memory")

// 12 ds_read_b128: full ks-slice (A quadrants 0,1 + B quadrants 0,1)
#define RD12(AA, BB, PRB, KX) do { _Pragma("unroll")                                     \
  for (int q = 0; q < 2; ++q) { _Pragma("unroll")                                        \
    for (int m = 0; m < 4; ++m)                                                          \
      AA[q*4+m] = *(const s16x8*)(smem + (PRB) + q*16384 + m*2048 + (aOff0 ^ (KX))); }   \
  _Pragma("unroll")                                                                      \
  for (int q = 0; q < 2; ++q) { _Pragma("unroll")                                        \
    for (int n = 0; n < 2; ++n)                                                          \
      BB[q*2+n] = *(const s16x8*)(smem + 65536 + (PRB) + q*16384 + n*2048 + (bOff0 ^ (KX))); } \
} while (0)

#define MFMA32(AA, BB) do { _Pragma("unroll")                                            \
  for (int q = 0; q < 2; ++q) { _Pragma("unroll")                                        \
    for (int m = 0; m < 4; ++m) { _Pragma("unroll")                                      \
      for (int p = 0; p < 2; ++p) { _Pragma("unroll")                                    \
        for (int n = 0; n < 2; ++n)                                                      \
          acc[q*4+m][p*2+n] = MFMA_BF16(AA[q*4+m], BB[p*2+n], acc[q*4+m][p*2+n]);        \
  } } } } while (0)

#define STAGE4(PWB, kn) do { _Pragma("unroll")                                           \
  for (int x = 0; x < 4; ++x) {                                                          \
    gll16(srcA0 + (size_t)ADROW[x] * K + (kn), smem + (PWB) + x*8192 + tt*16);           \
    gll16(srcB[x] + (kn), smem + 65536 + (PWB) + x*8192 + tt*16);                        \
  } } while (0)

// TILE: PRB = read-parity byte base, PWB = write-parity, T = k-tile idx, LAST literal 0/1
#define TILE(PRB, PWB, T, LAST) do {                                                     \
  /* ---- phase A: MFMA ks0 (Aa,Ba), prefetch ks1 (Ab,Bb), stage T+1 ---- */             \
  if constexpr (EPI == 1) {                                                              \
    const u16* kvp = Bt + (size_t)(4096 + w * 32 + li) * K + (T) * 64 + g * 8;           \
    bkv[0] = *(const s16x8*)(kvp);                                                       \
    bkv[1] = *(const s16x8*)(kvp + (size_t)16 * K);                                      \
    sa = *(const s16x8*)(smem + (PRB) + aKV);                                            \
  }                                                                                      \
  RD12(Ab, Bb, PRB, 64);                                                                 \
  if (!(LAST)) { STAGE4(PWB, ((T) + 1) * 64); }                                          \
  BARRIER;                                                                               \
  LGKM12;                                                                                \
  PRIO1; MFMA32(Aa, Ba);                                                                 \
  if constexpr (EPI == 1) {                                                              \
    acc_kv[0] = MFMA_BF16(sa, bkv[0], acc_kv[0]);                                        \
    acc_kv[1] = MFMA_BF16(sa, bkv[1], acc_kv[1]);                                        \
  }                                                                                      \
  PRIO0;                                                                                 \
  VM0;                                                                                   \
  BARRIER;                                                                               \
  /* ---- phase B: MFMA ks1 (Ab,Bb), prefetch next ks0 (Aa,Ba) from PWB ---- */          \
  if constexpr (EPI == 1) {                                                              \
    const u16* kvp = Bt + (size_t)(4096 + w * 32 + li) * K + (T) * 64 + g * 8;           \
    bkv[0] = *(const s16x8*)(kvp + 32);                                                  \
    bkv[1] = *(const s16x8*)(kvp + (size_t)16 * K + 32);                                 \
    sa = *(const s16x8*)(smem + (PRB) + (aKV ^ 64));                                     \
  }                                                                                      \
  if (!(LAST)) { RD12(Aa, Ba, PWB, 0); }                                                 \
  BARRIER;                                                                               \
  if (LAST) { LGKM0; } else { LGKM12; }                                                  \
  PRIO1; MFMA32(Ab, Bb);                                                                 \
  if constexpr (EPI == 1) {                                                              \
    acc_kv[0] = MFMA_BF16(sa, bkv[0], acc_kv[0]);                                        \
    acc_kv[1] = MFMA_BF16(sa, bkv[1], acc_kv[1]);                                        \
  }                                                                                      \
  PRIO0;                                                                                 \
  BARRIER;                                                                               \
} while (0)

template<int EPI>
__global__ __launch_bounds__(512, 2)
void gemm256_kernel(const u16* __restrict__ A, const u16* __restrict__ Bt,
                    float* __restrict__ Cf, u16* __restrict__ Cq,
                    u16* __restrict__ Ck, u16* __restrict__ Cvt,
                    int N, int K) {
  __shared__ __align__(16) char smem[131072];
  const int tt = threadIdx.x;
  const int w = tt >> 6, l = tt & 63;
  const int li = l & 15, g = l >> 4;
  const int wm = w >> 2, wn = w & 3;
  constexpr int ADROW[4] = {0, 128, 64, 192};

  // XCD-aware bijective swizzle (grid block-count is a multiple of 8)
  const int gx = gridDim.x;
  const int nwg = gx * gridDim.y;
  int id = blockIdx.y * gx + blockIdx.x;
  id = (id & 7) * (nwg >> 3) + (id >> 3);
  const int bn = id % gx, bm = id / gx;

  f32x4 acc[8][4];
#pragma unroll
  for (int i = 0; i < 8; ++i)
#pragma unroll
    for (int j = 0; j < 4; ++j) acc[i][j] = f4zero();
  f32x4 acc_kv[2];
  acc_kv[0] = f4zero(); acc_kv[1] = f4zero();

  // ---- staging source pointers (pre-permuted rows + inverse granule swizzle) ----
  const int q8 = (((tt & 7) ^ ((tt >> 3) & 7)) * 8);
  const u16* srcA0 = A + (size_t)(bm * 256 + (tt >> 3)) * K + q8;
  const u16* srcB[4];
#pragma unroll
  for (int x = 0; x < 4; ++x) {
    const int rho = x * 64 + (tt >> 3);
    const int qn_ = rho >> 7, rem = rho & 127;
    const int wn_ = rem >> 5, rr = rem & 31;
    const int brow = wn_ * 64 + qn_ * 32 + rr;
    srcB[x] = Bt + (size_t)(bn * 256 + brow) * K + q8;
  }

  // ---- ds_read per-thread byte offsets (granule XOR by row&7 == li&7) ----
  const int gr0 = (g ^ (li & 7)) * 16;
  const int aOff0 = wm * 8192 + li * 128 + gr0;
  const int bOff0 = wn * 4096 + li * 128 + gr0;
  // KV strip A-slice: global rows bn*16 + li -> QM'=(bn>>2)&1, wm'=bn>>3, mi2'=bn&3
  const int aKV = ((bn >> 2) & 1) * 16384 + (bn >> 3) * 8192 + (bn & 3) * 2048
                  + li * 128 + gr0;

  // operand register sets (rolling double buffer)
  s16x8 Aa[8], Ba[4], Ab[8], Bb[4];
  s16x8 bkv[2], sa;

  // ---- prologue: stage tile 0 into parity 0, drain, then issue R0(tile0) ----
  STAGE4(0, 0);
  VM0;
  BARRIER;
  RD12(Aa, Ba, 0, 0);

  // ---- main loop: 64 K-tiles (K == 4096), 2 per iteration ----
  for (int t2 = 0; t2 < 62; t2 += 2) {
    TILE(0, 32768, t2, 0);
    TILE(32768, 0, t2 + 1, 0);
  }
  TILE(0, 32768, 62, 0);   // tile 62, stages tile 63, prefetches its ks0
  TILE(32768, 0, 63, 1);   // tile 63 (no stage, no next prefetch)

  // ---- epilogue ----
#pragma unroll
  for (int mi = 0; mi < 8; ++mi) {
#pragma unroll
    for (int ni = 0; ni < 4; ++ni) {
      const int row0 = bm * 256 + wm * 128 + mi * 16 + g * 4;
      const int col = bn * 256 + wn * 64 + ni * 16 + li;
#pragma unroll
      for (int r = 0; r < 4; ++r) {
        const int m = row0 + r;
        const float v = acc[mi][ni][r];
        if (EPI == 0) {
          Cf[(size_t)m * N + col] = v;
        } else {
          Cq[(size_t)m * 4096 + col] = f2bf(v);
        }
      }
    }
  }
  if constexpr (EPI == 1) {
    // KV strip epilogue: rows bm*256 + bn*16 + g*4 + r, cols 4096 + w*32 + cs*16 + li
#pragma unroll
    for (int cs = 0; cs < 2; ++cs) {
      const int col = 4096 + w * 32 + cs * 16 + li;
#pragma unroll
      for (int r = 0; r < 4; ++r) {
        const int m = bm * 256 + bn * 16 + g * 4 + r;
        const float v = acc_kv[cs][r];
        const int bb2 = m >> 11, s = m & 2047;
        const int kt = s >> 5;
        const size_t tb = (size_t)(bb2 * 64 + kt);
        if (col < 4224) {
          const int d = col - 4096, kr = s & 31;
          const int mk = kr >> 4, lii = kr & 15;
          const int kk = d >> 5, gg = (d >> 3) & 3, e = d & 7;
          Ck[(tb * 8 + mk * 4 + kk) * 512 + (gg * 16 + lii) * 8 + e] = f2bf(v);
        } else {
          const int d = col - 4224, kp = s & 31;
          const int mf = d >> 4, lii = d & 15;
          const int gg = kp >> 3, e = kp & 7;
          Cvt[(tb * 8 + mf) * 512 + (gg * 16 + lii) * 8 + e] = f2bf(v);
        }
      }
    }
  }
}

// ---------------- flash attention (MQA) ----------------
// 1 wave/block; block p handles q-tiles {63-p, p} (uniform 66 tile-units).
// K double-buffered in registers; V issued at tile top; fragment-linear K/V loads.

__device__ __forceinline__ void load_ktile(s16x8 (&dst)[8], const u16* kf, size_t tb, int l) {
#pragma unroll
  for (int f = 0; f < 8; ++f)
    dst[f] = *(const s16x8*)&kf[(tb * 8 + f) * 512 + l * 8];
}

template<bool DIAG>
__device__ __forceinline__ void attn_tile(
    int kt, const u16* kf, const u16* vf, size_t bb64, int l, int li, int g,
    s16x8 (&use)[8], s16x8 (&fill)[8], bool do_fill,
    const s16x8 (&bq)[2][4], f32x4 (&acc)[8][2],
    float (&m_)[2], float (&lp)[2], float (&bias)[2],
    float c1, const float (&cjr)[8], float bstep, u16 (*Pw)[40]) {
  const size_t tb = bb64 + kt;
  s16x8 vr[8];
#pragma unroll
  for (int f = 0; f < 8; ++f)
    vr[f] = *(const s16x8*)&vf[(tb * 8 + f) * 512 + l * 8];
  if (do_fill) load_ktile(fill, kf, tb - 1, l);

  f32x4 sc[2][2];
  sc[0][0] = f4zero(); sc[0][1] = f4zero(); sc[1][0] = f4zero(); sc[1][1] = f4zero();
#pragma unroll
  for (int kk = 0; kk < 4; ++kk)
#pragma unroll
    for (int mk = 0; mk < 2; ++mk) {
      sc[mk][0] = MFMA_BF16(use[mk * 4 + kk], bq[0][kk], sc[mk][0]);
      sc[mk][1] = MFMA_BF16(use[mk * 4 + kk], bq[1][kk], sc[mk][1]);
    }

#pragma unroll
  for (int nq = 0; nq < 2; ++nq) {
    float sv[8];
    float pm = -3e38f;
    if (DIAG) {
#pragma unroll
      for (int mk = 0; mk < 2; ++mk)
#pragma unroll
        for (int r = 0; r < 4; ++r) {
          const int kd = mk * 16 + g * 4 + r - (nq * 16 + li);
          float s = fmaf(sc[mk][nq][r], c1, bias[nq] + cjr[mk * 4 + r]);
          s = (kd <= 0) ? s : -1e30f;
          sv[mk * 4 + r] = s;
          pm = fmaxf(pm, s);
        }
      pm = fmaxf(pm, __shfl_xor(pm, 16));
      pm = fmaxf(pm, __shfl_xor(pm, 32));
      m_[nq] = pm;
    } else {
#pragma unroll
      for (int mk = 0; mk < 2; ++mk)
#pragma unroll
        for (int r = 0; r < 4; ++r) {
          float s = fmaf(sc[mk][nq][r], c1, bias[nq] + cjr[mk * 4 + r]);
          sv[mk * 4 + r] = s;
          pm = fmaxf(pm, s);
        }
      if (__any(pm > m_[nq])) {
        pm = fmaxf(pm, __shfl_xor(pm, 16));
        pm = fmaxf(pm, __shfl_xor(pm, 32));
        const float nm = fmaxf(m_[nq], pm);
        const float scale = exp2f(m_[nq] - nm);
#pragma unroll
        for (int mf = 0; mf < 8; ++mf) acc[mf][nq] *= scale;
        lp[nq] *= scale;
        m_[nq] = nm;
      }
    }
    const float mref = m_[nq];
    float e[8];
#pragma unroll
    for (int j = 0; j < 8; ++j) e[j] = exp2f(sv[j] - mref);
    lp[nq] += ((e[0] + e[1]) + (e[2] + e[3])) + ((e[4] + e[5]) + (e[6] + e[7]));
#pragma unroll
    for (int mk = 0; mk < 2; ++mk) {
      uint2 wv;
      wv.x = pkbf(e[mk * 4 + 0], e[mk * 4 + 1]);
      wv.y = pkbf(e[mk * 4 + 2], e[mk * 4 + 3]);
      *reinterpret_cast<uint2*>(&Pw[nq * 16 + li][mk * 16 + g * 4]) = wv;
    }
    bias[nq] -= bstep;
  }

  s16x8 pb0 = *(const s16x8*)&Pw[li][g * 8];
  s16x8 pb1 = *(const s16x8*)&Pw[16 + li][g * 8];
#pragma unroll
  for (int mf = 0; mf < 8; ++mf) {
    acc[mf][0] = MFMA_BF16(vr[mf], pb0, acc[mf][0]);
    acc[mf][1] = MFMA_BF16(vr[mf], pb1, acc[mf][1]);
  }
}

__device__ __forceinline__ void attn_qtile(
    int qt, int h, int b, const u16* qbuf, const u16* kf, const u16* vf,
    u16* obuf, int l, int li, int g, float c1, float sl2, u16 (*Pw)[40]) {
  const int S = 2048;
  const int q0 = qt * 32;
  const size_t bb64 = (size_t)b * 64;

  s16x8 bq[2][4];
#pragma unroll
  for (int nq = 0; nq < 2; ++nq)
#pragma unroll
    for (int kk = 0; kk < 4; ++kk)
      bq[nq][kk] = *(const s16x8*)&qbuf[(size_t)(b * S + q0 + nq * 16 + li) * 4096
                                        + h * 128 + kk * 32 + g * 8];

  f32x4 acc[8][2];
#pragma unroll
  for (int mf = 0; mf < 8; ++mf) { acc[mf][0] = f4zero(); acc[mf][1] = f4zero(); }
  float m_[2] = {-3e38f, -3e38f};
  float lp[2] = {0.f, 0.f};

  float cjr[8];
#pragma unroll
  for (int j = 0; j < 8; ++j) cjr[j] = sl2 * (float)((j >> 2) * 16 + (j & 3));
  float bias[2];
#pragma unroll
  for (int nq = 0; nq < 2; ++nq)
    bias[nq] = sl2 * (float)(g * 4 - nq * 16 - li);
  const float bstep = sl2 * 32.f;

  s16x8 kA[8], kB[8];
  load_ktile(kA, kf, bb64 + qt, l);
  attn_tile<true>(qt, kf, vf, bb64, l, li, g, kA, kB, qt >= 1,
                  bq, acc, m_, lp, bias, c1, cjr, bstep, Pw);
  int kt = qt - 1;
  while (kt >= 1) {
    attn_tile<false>(kt, kf, vf, bb64, l, li, g, kB, kA, true,
                     bq, acc, m_, lp, bias, c1, cjr, bstep, Pw);
    attn_tile<false>(kt - 1, kf, vf, bb64, l, li, g, kA, kB, kt >= 2,
                     bq, acc, m_, lp, bias, c1, cjr, bstep, Pw);
    kt -= 2;
  }
  if (kt == 0)
    attn_tile<false>(0, kf, vf, bb64, l, li, g, kB, kA, false,
                     bq, acc, m_, lp, bias, c1, cjr, bstep, Pw);

#pragma unroll
  for (int nq = 0; nq < 2; ++nq) {
    float ls = lp[nq];
    ls += __shfl_xor(ls, 16);
    ls += __shfl_xor(ls, 32);
    const float inv = 1.f / ls;
    const size_t rowbase = (size_t)(b * S + q0 + nq * 16 + li) * 4096 + h * 128;
#pragma unroll
    for (int mf = 0; mf < 8; ++mf) {
      f32x4 v = acc[mf][nq];
      uint2 wv;
      wv.x = pkbf(v[0] * inv, v[1] * inv);
      wv.y = pkbf(v[2] * inv, v[3] * inv);
      *reinterpret_cast<uint2*>(&obuf[rowbase + mf * 16 + g * 4]) = wv;
    }
  }
}

__global__ __launch_bounds__(64, 2)
void attn_kernel(const u16* __restrict__ qbuf, const u16* __restrict__ kf,
                 const u16* __restrict__ vf, u16* __restrict__ obuf) {
  const int p = blockIdx.x, h = blockIdx.y, b = blockIdx.z;
  const int l = threadIdx.x, li = l & 15, g = l >> 4;
  const float L2E = 1.4426950408889634f;
  const float slope = exp2f(-0.25f * (float)(h + 1));
  const float c1 = 0.08838834764831845f * L2E;
  const float sl2 = slope * L2E;
  __shared__ __align__(16) u16 P[32][40];
  attn_qtile(63 - p, h, b, qbuf, kf, vf, obuf, l, li, g, c1, sl2, P);
  attn_qtile(p, h, b, qbuf, kf, vf, obuf, l, li, g, c1, sl2, P);
}

// ---------------- launch ----------------
extern "C" void kernel_launch(void* const* d_in, const int* in_sizes, int n_in,
                              void* d_out, int out_size, void* d_ws, size_t ws_size,
                              hipStream_t stream) {
  (void)in_sizes; (void)n_in; (void)out_size; (void)ws_size;
  const float* hidden = (const float*)d_in[0];
  const float* w_qkv = (const float*)d_in[1];
  const float* w_c = (const float*)d_in[2];
  float* out = (float*)d_out;
  char* ws = (char*)d_ws;

  // workspace layout (100 MB total)
  u16* hid_bf = (u16*)(ws + 0);            // 32 MB  (B*S,4096) bf16; reused as attn out
  u16* wT     = (u16*)(ws + 33554432);     // 34 MB  w_qkv^T then w_c^T (N,K) bf16
  u16* qbuf   = (u16*)(ws + 69206016);     // 32 MB  (B*S,4096) bf16
  u16* kbuf   = (u16*)(ws + 102760448);    // 1 MB   K fragment-linear
  u16* vtbuf  = (u16*)(ws + 103809024);    // 1 MB   V fragment-linear

  cvt_bf16_kernel<<<16384, 256, 0, stream>>>((const float4*)hidden, hid_bf, 4194304);
  transpose_cvt_kernel<<<dim3(136, 128), dim3(32, 8), 0, stream>>>(w_qkv, wT, 4096, 4352);
  gemm256_kernel<1><<<dim3(16, 16), 512, 0, stream>>>(hid_bf, wT, nullptr, qbuf, kbuf, vtbuf,
                                                      4352, 4096);
  attn_kernel<<<dim3(32, 32, 2), 64, 0, stream>>>(qbuf, kbuf, vtbuf, hid_bf);
  transpose_cvt_kernel<<<dim3(128, 128), dim3(32, 8), 0, stream>>>(w_c, wT, 4096, 4096);
  gemm256_kernel<0><<<dim3(16, 16), 512, 0, stream>>>(hid_bf, wT, out, nullptr, nullptr, nullptr,
                                                      4096, 4096);
}

// Round 10
// 467.610 us; speedup vs baseline: 1.8656x; 1.8656x over previous
//
#include <hip/hip_runtime.h>
#include <hip/hip_bf16.h>

typedef unsigned short u16;
typedef unsigned int u32;
typedef __attribute__((ext_vector_type(8))) short s16x8;
typedef __attribute__((ext_vector_type(4))) float f32x4;

#define MFMA_BF16(a, b, c) __builtin_amdgcn_mfma_f32_16x16x32_bf16(a, b, c, 0, 0, 0)

__device__ __forceinline__ u16 f2bf(float f) {
  union { float f; u32 u; } c; c.f = f;
  return (u16)((c.u + 0x7FFFu + ((c.u >> 16) & 1u)) >> 16);
}

__device__ __forceinline__ u32 pkbf(float a, float b) {
  float2 t; t.x = a; t.y = b;
  __hip_bfloat162 h = __float22bfloat162_rn(t);
  union { __hip_bfloat162 h; u32 u; } c; c.h = h; return c.u;
}

__device__ __forceinline__ void gll16(const void* g, void* l) {
  __builtin_amdgcn_global_load_lds((const __attribute__((address_space(1))) void*)g,
                                   (__attribute__((address_space(3))) void*)l, 16, 0, 0);
}

__device__ __forceinline__ f32x4 f4zero() { f32x4 z = {0.f, 0.f, 0.f, 0.f}; return z; }

// ---------------- prep: f32 -> bf16 convert ----------------
__global__ void cvt_bf16_kernel(const float4* __restrict__ in, u16* __restrict__ out, int n4) {
  int i = blockIdx.x * 256 + threadIdx.x;
  if (i >= n4) return;
  float4 v = in[i];
  uint2 w;
  w.x = (u32)f2bf(v.x) | ((u32)f2bf(v.y) << 16);
  w.y = (u32)f2bf(v.z) | ((u32)f2bf(v.w) << 16);
  *reinterpret_cast<uint2*>(out + (size_t)i * 4) = w;
}

// ---------------- prep: transpose + convert (R x C f32 -> C x R bf16) ----------------
__global__ void transpose_cvt_kernel(const float* __restrict__ in, u16* __restrict__ out,
                                     int R, int C) {
  __shared__ float tile[32][33];
  int tx = threadIdx.x, ty = threadIdx.y;
  int r0 = blockIdx.y * 32, c0 = blockIdx.x * 32;
#pragma unroll
  for (int i = 0; i < 32; i += 8)
    tile[ty + i][tx] = in[(size_t)(r0 + ty + i) * C + c0 + tx];
  __syncthreads();
#pragma unroll
  for (int i = 0; i < 32; i += 8)
    out[(size_t)(c0 + ty + i) * R + r0 + tx] = f2bf(tile[tx][ty + i]);
}

// =====================================================================================
// 256x256 GEMM, ONE barrier per K-tile (drift-pipelined):
//   per tile: [sa,bkv,RD a0/b0/b1 (16 ds) ; STAGE4 t+1] | Q00+KV0, Q01 | [bkv1, RD a1]
//             | Q11+KV1, Q10(b0 held) | sched_barrier ; VM0 ; BARRIER
// No mid-tile barriers: waves drift so one wave's LDS drain overlaps another's MFMA.
// Compiler inserts counted lgkmcnt for ds->MFMA deps (m97); manual waits: only VM0
// (gll16->ds_read dep is invisible to the compiler) before the single barrier.
// WAR ledger: reads of parity p all retire before their consuming MFMAs (compiler
// lgkm), which precede the tile-end sched_barrier(0)+VM0+BARRIER; S(t+2) into p is
// issued only after that barrier. RAW: S(t+1) drained by VM0 before next tile's reads.
// Live peak: 16 frags (a0/a1 8 + b0 4 + b1 4 overlap) + sa/bkv — R8-level VGPR.
// EPI 1 fuses the 256-col KV strip (grid exactly 16x16 = 256 blocks).
// =====================================================================================

#define BARRIER __builtin_amdgcn_s_barrier()
#define SCHEDB __builtin_amdgcn_sched_barrier(0)
#define PRIO1 __builtin_amdgcn_s_setprio(1)
#define PRIO0 __builtin_amdgcn_s_setprio(0)
#define VM0 asm volatile("s_waitcnt vmcnt(0)" ::: "memory")

#define RD_A(dst, PRB, QM) do { _Pragma("unroll")                                        \
  for (int mi2 = 0; mi2 < 4; ++mi2) {                                                    \
    dst[mi2][0] = *(const s16x8*)(smem + (PRB) + (QM)*16384 + mi2*2048 + aOff0);         \
    dst[mi2][1] = *(const s16x8*)(smem + (PRB) + (QM)*16384 + mi2*2048 + aOff1);         \
  } } while (0)

#define RD_B(dst, PRB, QN) do { _Pragma("unroll")                                        \
  for (int ni2 = 0; ni2 < 2; ++ni2) {                                                    \
    dst[ni2][0] = *(const s16x8*)(smem + 65536 + (PRB) + (QN)*16384 + ni2*2048 + bOff0); \
    dst[ni2][1] = *(const s16x8*)(smem + 65536 + (PRB) + (QN)*16384 + ni2*2048 + bOff1); \
  } } while (0)

#define MFMA_Q(QM, QN, Af, Bf) do { _Pragma("unroll")                                    \
  for (int ks = 0; ks < 2; ++ks) { _Pragma("unroll")                                     \
    for (int mi2 = 0; mi2 < 4; ++mi2) { _Pragma("unroll")                                \
      for (int ni2 = 0; ni2 < 2; ++ni2)                                                  \
        acc[(QM)*4+mi2][(QN)*2+ni2] =                                                    \
            MFMA_BF16(Af[mi2][ks], Bf[ni2][ks], acc[(QM)*4+mi2][(QN)*2+ni2]);            \
  } } } while (0)

#define STAGE4(PWB, kn) do { _Pragma("unroll")                                           \
  for (int x = 0; x < 4; ++x) {                                                          \
    gll16(srcA[x] + (kn), smem + (PWB) + x*8192 + tt*16);                                \
    gll16(srcB[x] + (kn), smem + 65536 + (PWB) + x*8192 + tt*16);                        \
  } } while (0)

#define TILE(PRB, PWB, T, LAST) do {                                                     \
  if constexpr (EPI == 1) {                                                              \
    kvp = Bt + (size_t)(4096 + w * 32 + li) * K + (T) * 64 + g * 8;                      \
    sa0 = *(const s16x8*)(smem + (PRB) + aKV);                                           \
    sa1 = *(const s16x8*)(smem + (PRB) + (aKV ^ 64));                                    \
    bkv0 = *(const s16x8*)(kvp);                                                         \
    bkv1 = *(const s16x8*)(kvp + (size_t)16 * K);                                        \
  }                                                                                      \
  RD_A(a0, PRB, 0); RD_B(b0, PRB, 0); RD_B(b1, PRB, 1);                                  \
  if (!(LAST)) { STAGE4(PWB, ((T) + 1) * 64); }                                          \
  SCHEDB;                                                                                \
  PRIO1; MFMA_Q(0, 0, a0, b0);                                                           \
  if constexpr (EPI == 1) {                                                              \
    acc_kv[0] = MFMA_BF16(sa0, bkv0, acc_kv[0]);                                         \
    acc_kv[1] = MFMA_BF16(sa0, bkv1, acc_kv[1]);                                         \
  }                                                                                      \
  MFMA_Q(0, 1, a0, b1); PRIO0;                                                           \
  SCHEDB;                                                                                \
  if constexpr (EPI == 1) {                                                              \
    bkv0 = *(const s16x8*)(kvp + 32);                                                    \
    bkv1 = *(const s16x8*)(kvp + (size_t)16 * K + 32);                                   \
  }                                                                                      \
  RD_A(a1, PRB, 1);                                                                      \
  PRIO1; MFMA_Q(1, 1, a1, b1);                                                           \
  if constexpr (EPI == 1) {                                                              \
    acc_kv[0] = MFMA_BF16(sa1, bkv0, acc_kv[0]);                                         \
    acc_kv[1] = MFMA_BF16(sa1, bkv1, acc_kv[1]);                                         \
  }                                                                                      \
  MFMA_Q(1, 0, a1, b0); PRIO0;                                                           \
  SCHEDB;                                                                                \
  VM0;                                                                                   \
  BARRIER;                                                                               \
} while (0)

template<int EPI>
__global__ __launch_bounds__(512, 2)
void gemm256_kernel(const u16* __restrict__ A, const u16* __restrict__ Bt,
                    float* __restrict__ Cf, u16* __restrict__ Cq,
                    u16* __restrict__ Ck, u16* __restrict__ Cvt,
                    int N, int K) {
  __shared__ __align__(16) char smem[131072];
  const int tt = threadIdx.x;
  const int w = tt >> 6, l = tt & 63;
  const int li = l & 15, g = l >> 4;
  const int wm = w >> 2, wn = w & 3;

  // XCD-aware bijective swizzle (grid block-count is a multiple of 8)
  const int gx = gridDim.x;
  const int nwg = gx * gridDim.y;
  int id = blockIdx.y * gx + blockIdx.x;
  id = (id & 7) * (nwg >> 3) + (id >> 3);
  const int bn = id % gx, bm = id / gx;

  f32x4 acc[8][4];
#pragma unroll
  for (int i = 0; i < 8; ++i)
#pragma unroll
    for (int j = 0; j < 4; ++j) acc[i][j] = f4zero();
  f32x4 acc_kv[2];
  acc_kv[0] = f4zero(); acc_kv[1] = f4zero();

  // ---- staging source pointers (pre-permuted rows + inverse granule swizzle) ----
  const int q8 = (((tt & 7) ^ ((tt >> 3) & 7)) * 8);
  const u16* srcA[4];
  const u16* srcB[4];
#pragma unroll
  for (int x = 0; x < 4; ++x) {
    const int arow = (x & 1) * 128 + (x >> 1) * 64 + (tt >> 3);
    srcA[x] = A + (size_t)(bm * 256 + arow) * K + q8;
    const int rho = x * 64 + (tt >> 3);
    const int qn_ = rho >> 7, rem = rho & 127;
    const int wn_ = rem >> 5, rr = rem & 31;
    const int brow = wn_ * 64 + qn_ * 32 + rr;
    srcB[x] = Bt + (size_t)(bn * 256 + brow) * K + q8;
  }

  // ---- ds_read per-thread byte offsets (granule XOR by row&7 == li&7) ----
  const int gr0 = (g ^ (li & 7)) * 16;
  const int aOff0 = wm * 8192 + li * 128 + gr0;
  const int aOff1 = aOff0 ^ 64;
  const int bOff0 = wn * 4096 + li * 128 + gr0;
  const int bOff1 = bOff0 ^ 64;
  // KV strip A-slice: global rows bn*16 + li -> QM'=(bn>>2)&1, wm'=bn>>3, mi2'=bn&3
  const int aKV = ((bn >> 2) & 1) * 16384 + (bn >> 3) * 8192 + (bn & 3) * 2048
                  + li * 128 + gr0;

  // operand registers (held across the tile; peak 16 fragments)
  s16x8 a0[4][2], a1[4][2], b0[2][2], b1[2][2];
  s16x8 sa0, sa1, bkv0, bkv1;
  const u16* kvp = nullptr;
  (void)kvp;

  // ---- prologue: stage tile 0 into parity 0, full drain + barrier ----
  STAGE4(0, 0);
  VM0;
  BARRIER;

  // ---- main loop: 64 K-tiles (K == 4096), 2 per iteration ----
  for (int t2 = 0; t2 < 62; t2 += 2) {
    TILE(0, 32768, t2, 0);
    TILE(32768, 0, t2 + 1, 0);
  }
  TILE(0, 32768, 62, 0);   // tile 62, stages tile 63
  TILE(32768, 0, 63, 1);   // tile 63 (no stage)

  // ---- epilogue ----
#pragma unroll
  for (int mi = 0; mi < 8; ++mi) {
#pragma unroll
    for (int ni = 0; ni < 4; ++ni) {
      const int row0 = bm * 256 + wm * 128 + mi * 16 + g * 4;
      const int col = bn * 256 + wn * 64 + ni * 16 + li;
#pragma unroll
      for (int r = 0; r < 4; ++r) {
        const int m = row0 + r;
        const float v = acc[mi][ni][r];
        if (EPI == 0) {
          Cf[(size_t)m * N + col] = v;
        } else {
          Cq[(size_t)m * 4096 + col] = f2bf(v);
        }
      }
    }
  }
  if constexpr (EPI == 1) {
    // KV strip epilogue: rows bm*256 + bn*16 + g*4 + r, cols 4096 + w*32 + cs*16 + li
#pragma unroll
    for (int cs = 0; cs < 2; ++cs) {
      const int col = 4096 + w * 32 + cs * 16 + li;
#pragma unroll
      for (int r = 0; r < 4; ++r) {
        const int m = bm * 256 + bn * 16 + g * 4 + r;
        const float v = acc_kv[cs][r];
        const int bb2 = m >> 11, s = m & 2047;
        const int kt = s >> 5;
        const size_t tb = (size_t)(bb2 * 64 + kt);
        if (col < 4224) {
          const int d = col - 4096, kr = s & 31;
          const int mk = kr >> 4, lii = kr & 15;
          const int kk = d >> 5, gg = (d >> 3) & 3, e = d & 7;
          Ck[(tb * 8 + mk * 4 + kk) * 512 + (gg * 16 + lii) * 8 + e] = f2bf(v);
        } else {
          const int d = col - 4224, kp = s & 31;
          const int mf = d >> 4, lii = d & 15;
          const int gg = kp >> 3, e = kp & 7;
          Cvt[(tb * 8 + mf) * 512 + (gg * 16 + lii) * 8 + e] = f2bf(v);
        }
      }
    }
  }
}

// ---------------- flash attention (MQA) ----------------
// 1 wave/block; block p handles q-tiles {63-p, p} (uniform 66 tile-units).
// K double-buffered in registers; V issued at tile top; fragment-linear K/V loads.

__device__ __forceinline__ void load_ktile(s16x8 (&dst)[8], const u16* kf, size_t tb, int l) {
#pragma unroll
  for (int f = 0; f < 8; ++f)
    dst[f] = *(const s16x8*)&kf[(tb * 8 + f) * 512 + l * 8];
}

template<bool DIAG>
__device__ __forceinline__ void attn_tile(
    int kt, const u16* kf, const u16* vf, size_t bb64, int l, int li, int g,
    s16x8 (&use)[8], s16x8 (&fill)[8], bool do_fill,
    const s16x8 (&bq)[2][4], f32x4 (&acc)[8][2],
    float (&m_)[2], float (&lp)[2], float (&bias)[2],
    float c1, const float (&cjr)[8], float bstep, u16 (*Pw)[40]) {
  const size_t tb = bb64 + kt;
  s16x8 vr[8];
#pragma unroll
  for (int f = 0; f < 8; ++f)
    vr[f] = *(const s16x8*)&vf[(tb * 8 + f) * 512 + l * 8];
  if (do_fill) load_ktile(fill, kf, tb - 1, l);

  f32x4 sc[2][2];
  sc[0][0] = f4zero(); sc[0][1] = f4zero(); sc[1][0] = f4zero(); sc[1][1] = f4zero();
#pragma unroll
  for (int kk = 0; kk < 4; ++kk)
#pragma unroll
    for (int mk = 0; mk < 2; ++mk) {
      sc[mk][0] = MFMA_BF16(use[mk * 4 + kk], bq[0][kk], sc[mk][0]);
      sc[mk][1] = MFMA_BF16(use[mk * 4 + kk], bq[1][kk], sc[mk][1]);
    }

#pragma unroll
  for (int nq = 0; nq < 2; ++nq) {
    float sv[8];
    float pm = -3e38f;
    if (DIAG) {
#pragma unroll
      for (int mk = 0; mk < 2; ++mk)
#pragma unroll
        for (int r = 0; r < 4; ++r) {
          const int kd = mk * 16 + g * 4 + r - (nq * 16 + li);
          float s = fmaf(sc[mk][nq][r], c1, bias[nq] + cjr[mk * 4 + r]);
          s = (kd <= 0) ? s : -1e30f;
          sv[mk * 4 + r] = s;
          pm = fmaxf(pm, s);
        }
      pm = fmaxf(pm, __shfl_xor(pm, 16));
      pm = fmaxf(pm, __shfl_xor(pm, 32));
      m_[nq] = pm;
    } else {
#pragma unroll
      for (int mk = 0; mk < 2; ++mk)
#pragma unroll
        for (int r = 0; r < 4; ++r) {
          float s = fmaf(sc[mk][nq][r], c1, bias[nq] + cjr[mk * 4 + r]);
          sv[mk * 4 + r] = s;
          pm = fmaxf(pm, s);
        }
      if (__any(pm > m_[nq])) {
        pm = fmaxf(pm, __shfl_xor(pm, 16));
        pm = fmaxf(pm, __shfl_xor(pm, 32));
        const float nm = fmaxf(m_[nq], pm);
        const float scale = exp2f(m_[nq] - nm);
#pragma unroll
        for (int mf = 0; mf < 8; ++mf) acc[mf][nq] *= scale;
        lp[nq] *= scale;
        m_[nq] = nm;
      }
    }
    const float mref = m_[nq];
    float e[8];
#pragma unroll
    for (int j = 0; j < 8; ++j) e[j] = exp2f(sv[j] - mref);
    lp[nq] += ((e[0] + e[1]) + (e[2] + e[3])) + ((e[4] + e[5]) + (e[6] + e[7]));
#pragma unroll
    for (int mk = 0; mk < 2; ++mk) {
      uint2 wv;
      wv.x = pkbf(e[mk * 4 + 0], e[mk * 4 + 1]);
      wv.y = pkbf(e[mk * 4 + 2], e[mk * 4 + 3]);
      *reinterpret_cast<uint2*>(&Pw[nq * 16 + li][mk * 16 + g * 4]) = wv;
    }
    bias[nq] -= bstep;
  }

  s16x8 pb0 = *(const s16x8*)&Pw[li][g * 8];
  s16x8 pb1 = *(const s16x8*)&Pw[16 + li][g * 8];
#pragma unroll
  for (int mf = 0; mf < 8; ++mf) {
    acc[mf][0] = MFMA_BF16(vr[mf], pb0, acc[mf][0]);
    acc[mf][1] = MFMA_BF16(vr[mf], pb1, acc[mf][1]);
  }
}

__device__ __forceinline__ void attn_qtile(
    int qt, int h, int b, const u16* qbuf, const u16* kf, const u16* vf,
    u16* obuf, int l, int li, int g, float c1, float sl2, u16 (*Pw)[40]) {
  const int S = 2048;
  const int q0 = qt * 32;
  const size_t bb64 = (size_t)b * 64;

  s16x8 bq[2][4];
#pragma unroll
  for (int nq = 0; nq < 2; ++nq)
#pragma unroll
    for (int kk = 0; kk < 4; ++kk)
      bq[nq][kk] = *(const s16x8*)&qbuf[(size_t)(b * S + q0 + nq * 16 + li) * 4096
                                        + h * 128 + kk * 32 + g * 8];

  f32x4 acc[8][2];
#pragma unroll
  for (int mf = 0; mf < 8; ++mf) { acc[mf][0] = f4zero(); acc[mf][1] = f4zero(); }
  float m_[2] = {-3e38f, -3e38f};
  float lp[2] = {0.f, 0.f};

  float cjr[8];
#pragma unroll
  for (int j = 0; j < 8; ++j) cjr[j] = sl2 * (float)((j >> 2) * 16 + (j & 3));
  float bias[2];
#pragma unroll
  for (int nq = 0; nq < 2; ++nq)
    bias[nq] = sl2 * (float)(g * 4 - nq * 16 - li);
  const float bstep = sl2 * 32.f;

  s16x8 kA[8], kB[8];
  load_ktile(kA, kf, bb64 + qt, l);
  attn_tile<true>(qt, kf, vf, bb64, l, li, g, kA, kB, qt >= 1,
                  bq, acc, m_, lp, bias, c1, cjr, bstep, Pw);
  int kt = qt - 1;
  while (kt >= 1) {
    attn_tile<false>(kt, kf, vf, bb64, l, li, g, kB, kA, true,
                     bq, acc, m_, lp, bias, c1, cjr, bstep, Pw);
    attn_tile<false>(kt - 1, kf, vf, bb64, l, li, g, kA, kB, kt >= 2,
                     bq, acc, m_, lp, bias, c1, cjr, bstep, Pw);
    kt -= 2;
  }
  if (kt == 0)
    attn_tile<false>(0, kf, vf, bb64, l, li, g, kB, kA, false,
                     bq, acc, m_, lp, bias, c1, cjr, bstep, Pw);

#pragma unroll
  for (int nq = 0; nq < 2; ++nq) {
    float ls = lp[nq];
    ls += __shfl_xor(ls, 16);
    ls += __shfl_xor(ls, 32);
    const float inv = 1.f / ls;
    const size_t rowbase = (size_t)(b * S + q0 + nq * 16 + li) * 4096 + h * 128;
#pragma unroll
    for (int mf = 0; mf < 8; ++mf) {
      f32x4 v = acc[mf][nq];
      uint2 wv;
      wv.x = pkbf(v[0] * inv, v[1] * inv);
      wv.y = pkbf(v[2] * inv, v[3] * inv);
      *reinterpret_cast<uint2*>(&obuf[rowbase + mf * 16 + g * 4]) = wv;
    }
  }
}

__global__ __launch_bounds__(64, 2)
void attn_kernel(const u16* __restrict__ qbuf, const u16* __restrict__ kf,
                 const u16* __restrict__ vf, u16* __restrict__ obuf) {
  const int p = blockIdx.x, h = blockIdx.y, b = blockIdx.z;
  const int l = threadIdx.x, li = l & 15, g = l >> 4;
  const float L2E = 1.4426950408889634f;
  const float slope = exp2f(-0.25f * (float)(h + 1));
  const float c1 = 0.08838834764831845f * L2E;
  const float sl2 = slope * L2E;
  __shared__ __align__(16) u16 P[32][40];
  attn_qtile(63 - p, h, b, qbuf, kf, vf, obuf, l, li, g, c1, sl2, P);
  attn_qtile(p, h, b, qbuf, kf, vf, obuf, l, li, g, c1, sl2, P);
}

// ---------------- launch ----------------
extern "C" void kernel_launch(void* const* d_in, const int* in_sizes, int n_in,
                              void* d_out, int out_size, void* d_ws, size_t ws_size,
                              hipStream_t stream) {
  (void)in_sizes; (void)n_in; (void)out_size; (void)ws_size;
  const float* hidden = (const float*)d_in[0];
  const float* w_qkv = (const float*)d_in[1];
  const float* w_c = (const float*)d_in[2];
  float* out = (float*)d_out;
  char* ws = (char*)d_ws;

  // workspace layout (100 MB total)
  u16* hid_bf = (u16*)(ws + 0);            // 32 MB  (B*S,4096) bf16; reused as attn out
  u16* wT     = (u16*)(ws + 33554432);     // 34 MB  w_qkv^T then w_c^T (N,K) bf16
  u16* qbuf   = (u16*)(ws + 69206016);     // 32 MB  (B*S,4096) bf16
  u16* kbuf   = (u16*)(ws + 102760448);    // 1 MB   K fragment-linear
  u16* vtbuf  = (u16*)(ws + 103809024);    // 1 MB   V fragment-linear

  cvt_bf16_kernel<<<16384, 256, 0, stream>>>((const float4*)hidden, hid_bf, 4194304);
  transpose_cvt_kernel<<<dim3(136, 128), dim3(32, 8), 0, stream>>>(w_qkv, wT, 4096, 4352);
  gemm256_kernel<1><<<dim3(16, 16), 512, 0, stream>>>(hid_bf, wT, nullptr, qbuf, kbuf, vtbuf,
                                                      4352, 4096);
  attn_kernel<<<dim3(32, 32, 2), 64, 0, stream>>>(qbuf, kbuf, vtbuf, hid_bf);
  transpose_cvt_kernel<<<dim3(128, 128), dim3(32, 8), 0, stream>>>(w_c, wT, 4096, 4096);
  gemm256_kernel<0><<<dim3(16, 16), 512, 0, stream>>>(hid_bf, wT, out, nullptr, nullptr, nullptr,
                                                      4096, 4096);
}